// Round 7
// baseline (455.196 us; speedup 1.0000x reference)
//
#include <hip/hip_runtime.h>
#include <cstdint>
#include <cstddef>

using u16 = unsigned short;
typedef short short8 __attribute__((ext_vector_type(8)));
typedef unsigned short us8 __attribute__((ext_vector_type(8)));
typedef unsigned short us4 __attribute__((ext_vector_type(4)));
typedef float f32x4 __attribute__((ext_vector_type(4)));
typedef float f4 __attribute__((ext_vector_type(4)));

#define T_ 1024
#define B_ 8
#define H_ 1024
#define HEADS_ 16
#define HD_ 64
#define N3_ 3072

__device__ __forceinline__ float b2f(u16 u){
  union { float f; unsigned int i; } v; v.i = ((unsigned int)u) << 16; return v.f;
}
// fast bf16 convert: round-half-up
__device__ __forceinline__ u16 f2b(float f){
  union { float f; unsigned int i; } v; v.f = f;
  return (u16)((v.i + 0x8000u) >> 16);
}

// ---------------- GEMM (unchanged from passing rounds) ----------------
template<bool HAS_S, bool SCALE_A, bool POS_A, bool A_BF16, bool OUT_F32>
__global__ __launch_bounds__(256) void k_gemm(const void* __restrict__ A_, const float* __restrict__ W,
                                              const float* __restrict__ RA, const float* __restrict__ S,
                                              const float* __restrict__ bias, void* __restrict__ C_, int N){
  const int K = 1024;
  const int n0 = blockIdx.x * 128, m0 = blockIdx.y * 128;
  const int tid = threadIdx.x, lane = tid & 63;
  const int wave = tid >> 6, wr = wave >> 1, wc = wave & 1;
  __shared__ alignas(16) u16 At[128 * 32];
  __shared__ alignas(16) u16 Bt[128 * 32];
  f32x4 acc[4][4] = {};

  for (int kt = 0; kt < 32; ++kt){
    const int k0 = kt * 32;
    f4 wv[4];
    us8 avb[2];
    f4 avf[4];
#pragma unroll
    for (int i = 0; i < 4; ++i){
      int c = tid + i * 256, r = c >> 3, sg = c & 7;
      wv[i] = *(const f4*)(W + (size_t)(n0 + r) * K + k0 + sg * 4);
    }
    if (A_BF16){
      const u16* A = (const u16*)A_;
#pragma unroll
      for (int i = 0; i < 2; ++i){
        int c = tid + i * 256, r = c >> 2, sg = c & 3;
        avb[i] = *(const us8*)(A + (size_t)(m0 + r) * K + k0 + sg * 8);
      }
    } else {
      const float* A = (const float*)A_;
#pragma unroll
      for (int i = 0; i < 4; ++i){
        int c = tid + i * 256, r = c >> 3, sg = c & 7;
        int m = m0 + r;
        const float* ap = POS_A ? (A + (size_t)(m >> 3) * K + k0 + sg * 4)
                                : (A + (size_t)m * K + k0 + sg * 4);
        avf[i] = *(const f4*)ap;
        if (SCALE_A){
          f4 rv = *(const f4*)(RA + (m & 7) * K + k0 + sg * 4);
          avf[i] = avf[i] * rv;
        }
      }
    }
    __syncthreads();
#pragma unroll
    for (int i = 0; i < 4; ++i){
      int c = tid + i * 256, r = c >> 3, sg = c & 7;
      us4 pw;
#pragma unroll
      for (int u = 0; u < 4; ++u) pw[u] = f2b(wv[i][u]);
      *(us4*)(Bt + r * 32 + sg * 4) = pw;
    }
    if (A_BF16){
#pragma unroll
      for (int i = 0; i < 2; ++i){
        int c = tid + i * 256, r = c >> 2, sg = c & 3;
        *(us8*)(At + r * 32 + sg * 8) = avb[i];
      }
    } else {
#pragma unroll
      for (int i = 0; i < 4; ++i){
        int c = tid + i * 256, r = c >> 3, sg = c & 7;
        us4 pa;
#pragma unroll
        for (int u = 0; u < 4; ++u) pa[u] = f2b(avf[i][u]);
        *(us4*)(At + r * 32 + sg * 4) = pa;
      }
    }
    __syncthreads();
    short8 af[4], bf[4];
#pragma unroll
    for (int i = 0; i < 4; ++i){
      int ar = wr * 64 + i * 16 + (lane & 15);
      af[i] = *(const short8*)(At + ar * 32 + ((lane >> 4) << 3));
      int br = wc * 64 + i * 16 + (lane & 15);
      bf[i] = *(const short8*)(Bt + br * 32 + ((lane >> 4) << 3));
    }
#pragma unroll
    for (int i = 0; i < 4; ++i)
#pragma unroll
      for (int j = 0; j < 4; ++j)
        acc[i][j] = __builtin_amdgcn_mfma_f32_16x16x32_bf16(af[i], bf[j], acc[i][j], 0, 0, 0);
  }
#pragma unroll
  for (int i = 0; i < 4; ++i){
    int row0 = wr * 64 + i * 16 + ((lane >> 4) << 2);
#pragma unroll
    for (int j = 0; j < 4; ++j){
      int o = n0 + wc * 64 + j * 16 + (lane & 15);
      float bv = bias[o];
#pragma unroll
      for (int jj = 0; jj < 4; ++jj){
        int m = m0 + row0 + jj;
        float v = acc[i][j][jj];
        if (HAS_S) v *= S[(m & 7) * N + o];
        v += bv;
        if (OUT_F32) ((float*)C_)[(size_t)m * N + o] = v;
        else         ((u16*)C_)[(size_t)m * N + o] = f2b(v);
      }
    }
  }
}

// ---------------- V transpose to global: VT[n][d][t] <- qkv[t, b, head*192+128+d] ----------------
__global__ __launch_bounds__(256) void k_vt(const u16* __restrict__ qkv, u16* __restrict__ VT){
  const int tt = blockIdx.x;
  const int n = blockIdx.y;
  const int b = n >> 4, head = n & 15;
  __shared__ alignas(16) u16 tile[64][72];
  const int tid = threadIdx.x;
#pragma unroll
  for (int i = 0; i < 2; ++i){
    int c = tid + i * 256;
    int r = c >> 3, sg = c & 7;
    const u16* src = qkv + ((size_t)(tt * 64 + r) * 8 + b) * N3_ + head * 192 + 128 + sg * 8;
    *(us8*)&tile[r][sg * 8] = *(const us8*)src;
  }
  __syncthreads();
#pragma unroll
  for (int i = 0; i < 2; ++i){
    int c = tid + i * 256;
    int d = c >> 3, sg = c & 7;
    us8 ov;
#pragma unroll
    for (int u = 0; u < 8; ++u) ov[u] = tile[sg * 8 + u][d];
    *(us8*)(VT + ((size_t)n * 64 + d) * 1024 + tt * 64 + sg * 8) = ov;
  }
}

// ---------------- fused attention ----------------
// 1-D grid 4096, XCD-swizzled: xcd = b&7 owns n = (b&7)+((b>>8)<<3); qb = (b>>3)&31.
// Per XCD scheduling round: ONE n x 32 qb -> K/V/rk (384KB) L2-resident, 32x reuse.
#define G_OFF   0           // flat g, 33*1025*2 = 67650 B ; Phase D: Pt_w overlay (8 x 8192)
#define KV_OFF  67856       // staging 65536 B ; Phase D: VT[64][512] then f32 partials
#define RWQ_OFF 133392      // 32 x 128B
#define RRQ_OFF 137488      // 48 x 128B
#define RED_OFF 143632      // 544 floats
#define SMEM_SZ 145808

__device__ __forceinline__ int gswz(int byt){ return byt ^ (((byt >> 13) & 3) << 5); }

__global__ __launch_bounds__(512, 1) void k_attn(const u16* __restrict__ qkv, const u16* __restrict__ rk,
                                                 const u16* __restrict__ VTg, const float* __restrict__ rwb,
                                                 const float* __restrict__ rrb, u16* __restrict__ ctx){
  const int bid = blockIdx.x;
  const int n = (bid & 7) + ((bid >> 8) << 3);
  const int qb = (bid >> 3) & 31;
  const int q0 = qb * 32;
  const int bat = n >> 4, head = n & 15;
  const int tid = threadIdx.x, lane = tid & 63, wave = tid >> 6;
  const int l15 = lane & 15, grp = lane >> 4;

  __shared__ alignas(16) char smem[SMEM_SZ];
  char* gB  = smem + G_OFF;
  char* kvS = smem + KV_OFF;
  u16* rwq = (u16*)(smem + RWQ_OFF);
  u16* rrq = (u16*)(smem + RRQ_OFF);
  float* redf = (float*)(smem + RED_OFF);

  us8 stv[8];

  // ---- issue rk seg0 loads first (hide under Phase A)
#pragma unroll
  for (int i = 0; i < 8; ++i){ int c = tid + i * 512, r = c >> 3, sg = c & 7;
    stv[i] = *(const us8*)(rk + ((size_t)r * 8 + bat) * 1024 + head * 64 + sg * 8); }

  // ---- Phase A: rw_q + rr_q, bias added, pre-scaled by 0.125*log2(e) (exp2 domain)
  const float PRESCALE = 0.125f * 1.44269504089f;
#pragma unroll
  for (int rep = 0; rep < 2; ++rep){
    int c = tid + rep * 512;
    if (c < 640){
      int s = c >> 3, sg = c & 7;
      u16* dst; int row; const float* bias;
      if (s < 32){ dst = rwq; row = s; bias = rwb; }
      else       { dst = rrq; row = s - 32; bias = rrb; }
      int qrow = q0 + row;
      float v[8];
      const float* bp2 = bias + head * 64 + sg * 8;
      if (qrow < T_){
        const u16* qp = qkv + ((size_t)qrow * 8 + bat) * N3_ + head * 192 + sg * 8;
        us8 qv = *(const us8*)qp;
        f4 b0 = *(const f4*)bp2, b1 = *(const f4*)(bp2 + 4);
#pragma unroll
        for (int u = 0; u < 4; ++u){
          v[u]     = (b2f(qv[u])     + b0[u]) * PRESCALE;
          v[u + 4] = (b2f(qv[u + 4]) + b1[u]) * PRESCALE;
        }
      } else {
#pragma unroll
        for (int u = 0; u < 8; ++u) v[u] = 0.f;
      }
      us8 pk;
#pragma unroll
      for (int u = 0; u < 8; ++u) pk[u] = f2b(v[u]);
      *(us8*)((char*)dst + row * 128 + ((sg * 16) ^ ((row & 7) << 4))) = pk;
    }
  }
  if (tid < 33) *(u16*)(gB + gswz(tid * 2050 + 2048)) = 0;

  auto ldf = [&](const void* base, int row, int kkb)->short8 {
    int co = kkb + (grp << 4);
    return *(const short8*)((const char*)base + row * 128 + (co ^ ((row & 7) << 4)));
  };
  auto stageKV = [&](){
#pragma unroll
    for (int i = 0; i < 8; ++i){ int c = tid + i * 512, r = c >> 3, sg = c & 7;
      *(us8*)(kvS + r * 128 + ((sg * 16) ^ ((r & 7) << 4))) = stv[i]; }
  };
  auto computeB = [&](int s){
    short8 af[3][2];
#pragma unroll
    for (int pi = 0; pi < 3; ++pi)
#pragma unroll
      for (int kk = 0; kk < 2; ++kk) af[pi][kk] = ldf(rrq, pi * 16 + l15, kk * 64);
#pragma unroll
    for (int c4 = 0; c4 < 4; ++c4){
      int brow = wave * 64 + c4 * 16 + l15;
      short8 bf0 = ldf(kvS, brow, 0), bf1 = ldf(kvS, brow, 64);
      int rg = s * 512 + wave * 64 + c4 * 16 + l15;
#pragma unroll
      for (int pi = 0; pi < 3; ++pi){
        f32x4 acc = {0.f, 0.f, 0.f, 0.f};
        acc = __builtin_amdgcn_mfma_f32_16x16x32_bf16(af[pi][0], bf0, acc, 0, 0, 0);
        acc = __builtin_amdgcn_mfma_f32_16x16x32_bf16(af[pi][1], bf1, acc, 0, 0, 0);
#pragma unroll
        for (int jj = 0; jj < 4; ++jj){
          int a = pi * 16 + (grp << 2) + jj;
          if (a < 33) *(u16*)(gB + gswz(a * 2050 + (rg << 1))) = f2b(acc[jj]);
        }
      }
    }
  };

  // ---- Phase B
  __syncthreads();                 // Phase A + zero slots visible
  stageKV();                       // rk seg0
#pragma unroll
  for (int i = 0; i < 8; ++i){ int c = tid + i * 512, r = c >> 3, sg = c & 7;
    stv[i] = *(const us8*)(rk + ((size_t)(512 + r) * 8 + bat) * 1024 + head * 64 + sg * 8); }
  __syncthreads();                 // seg0 staged
  computeB(0);
  __syncthreads();                 // seg0 readers done
  stageKV();                       // rk seg1
#pragma unroll
  for (int i = 0; i < 8; ++i){ int c = tid + i * 512, r = c >> 3, sg = c & 7;
    stv[i] = *(const us8*)(qkv + ((size_t)r * 8 + bat) * N3_ + head * 192 + 64 + sg * 8); }  // K seg0 prefetch
  __syncthreads();                 // seg1 staged
  computeB(1);

  // ---- Phase C
  f32x4 p[2][2][4];
  float pm[2][4];
#pragma unroll
  for (int m = 0; m < 2; ++m)
#pragma unroll
    for (int jj = 0; jj < 4; ++jj) pm[m][jj] = -3.0e38f;

  auto computeC = [&](int s){
    short8 af[2][2];
#pragma unroll
    for (int m = 0; m < 2; ++m)
#pragma unroll
      for (int kk = 0; kk < 2; ++kk) af[m][kk] = ldf(rwq, m * 16 + l15, kk * 64);
#pragma unroll
    for (int c4 = 0; c4 < 4; ++c4){
      int brow = wave * 64 + c4 * 16 + l15;
      short8 bf0 = ldf(kvS, brow, 0), bf1 = ldf(kvS, brow, 64);
      int bcol = s * 512 + wave * 64 + c4 * 16 + l15;
      int byt0 = ((1023 - q0 + bcol) << 1) + (grp << 13);
#pragma unroll
      for (int m = 0; m < 2; ++m){
        f32x4 acc = {0.f, 0.f, 0.f, 0.f};
        acc = __builtin_amdgcn_mfma_f32_16x16x32_bf16(af[m][0], bf0, acc, 0, 0, 0);
        acc = __builtin_amdgcn_mfma_f32_16x16x32_bf16(af[m][1], bf1, acc, 0, 0, 0);
#pragma unroll
        for (int jj = 0; jj < 4; ++jj){
          int byt = byt0 + (m << 15) + (jj << 11);
          float gv = b2f(*(const u16*)(gB + gswz(byt)));
          float sc = acc[jj] + gv;
          p[s][m][c4][jj] = sc;
          pm[m][jj] = fmaxf(pm[m][jj], sc);
        }
      }
    }
  };

  __syncthreads();                 // B seg1 readers done, gS complete
  stageKV();                       // K seg0
#pragma unroll
  for (int i = 0; i < 8; ++i){ int c = tid + i * 512, r = c >> 3, sg = c & 7;
    stv[i] = *(const us8*)(qkv + ((size_t)(512 + r) * 8 + bat) * N3_ + head * 192 + 64 + sg * 8); }
  __syncthreads();                 // K seg0 staged
  computeC(0);
  __syncthreads();                 // seg0 readers done
  stageKV();                       // K seg1
  __syncthreads();                 // K seg1 staged
  computeC(1);

  // ---- softmax (exact two-pass, exp2 domain)
#pragma unroll
  for (int m = 0; m < 2; ++m)
#pragma unroll
    for (int jj = 0; jj < 4; ++jj)
#pragma unroll
      for (int mk = 1; mk < 16; mk <<= 1) pm[m][jj] = fmaxf(pm[m][jj], __shfl_xor(pm[m][jj], mk));
  __syncthreads();                 // Phase C kvS/gS readers done
  // VT seg0 prefetch (hidden under softmax reduction)
#pragma unroll
  for (int i = 0; i < 8; ++i){ int c = tid + i * 512, d = c >> 6, tc = c & 63;
    stv[i] = *(const us8*)(VTg + ((size_t)n * 64 + d) * 1024 + tc * 8); }
  if (l15 == 0){
#pragma unroll
    for (int m = 0; m < 2; ++m)
#pragma unroll
      for (int jj = 0; jj < 4; ++jj) redf[wave * 32 + m * 16 + (grp << 2) + jj] = pm[m][jj];
  }
  __syncthreads();
  float M_[2][4];
#pragma unroll
  for (int m = 0; m < 2; ++m)
#pragma unroll
    for (int jj = 0; jj < 4; ++jj){
      int row = m * 16 + (grp << 2) + jj;
      float v = redf[row];
#pragma unroll
      for (int w = 1; w < 8; ++w) v = fmaxf(v, redf[w * 32 + row]);
      M_[m][jj] = v;
    }
  // stage VT seg0 (kvS free since first softmax sync), issue VT seg1 loads
#pragma unroll
  for (int i = 0; i < 8; ++i){ int c = tid + i * 512, d = c >> 6, tc = c & 63;
    *(us8*)(kvS + d * 1024 + ((tc * 16) ^ ((d & 31) << 4))) = stv[i]; }
#pragma unroll
  for (int i = 0; i < 8; ++i){ int c = tid + i * 512, d = c >> 6, tc = c & 63;
    stv[i] = *(const us8*)(VTg + ((size_t)n * 64 + d) * 1024 + 512 + tc * 8); }

  float L_[2][4] = {};
#pragma unroll
  for (int s = 0; s < 2; ++s)
#pragma unroll
    for (int m = 0; m < 2; ++m)
#pragma unroll
      for (int c4 = 0; c4 < 4; ++c4)
#pragma unroll
        for (int jj = 0; jj < 4; ++jj){
          float e = __builtin_exp2f(p[s][m][c4][jj] - M_[m][jj]);
          p[s][m][c4][jj] = e;
          L_[m][jj] += e;
        }
#pragma unroll
  for (int m = 0; m < 2; ++m)
#pragma unroll
    for (int jj = 0; jj < 4; ++jj)
#pragma unroll
      for (int mk = 1; mk < 16; mk <<= 1) L_[m][jj] += __shfl_xor(L_[m][jj], mk);
  if (l15 == 0){
#pragma unroll
    for (int m = 0; m < 2; ++m)
#pragma unroll
      for (int jj = 0; jj < 4; ++jj) redf[256 + wave * 32 + m * 16 + (grp << 2) + jj] = L_[m][jj];
  }
  __syncthreads();
  if (wave == 0 && l15 == 0){
#pragma unroll
    for (int m = 0; m < 2; ++m)
#pragma unroll
      for (int jj = 0; jj < 4; ++jj){
        int row = m * 16 + (grp << 2) + jj;
        float sum = 0.f;
#pragma unroll
        for (int w = 0; w < 8; ++w) sum += redf[256 + w * 32 + row];
        redf[512 + row] = 1.0f / (sum + 1e-20f);
      }
  }

  // ---- Phase D: O = P x V. Pt per-wave private (gS overlay; gS dead since softmax sync1).
  char* ptW = smem + G_OFF + wave * 8192;
#pragma unroll
  for (int s = 0; s < 2; ++s)
#pragma unroll
    for (int m = 0; m < 2; ++m)
#pragma unroll
      for (int c4 = 0; c4 < 4; ++c4)
#pragma unroll
        for (int jj = 0; jj < 4; ++jj){
          int q = m * 16 + (grp << 2) + jj;
          int tl = s * 64 + c4 * 16 + l15;
          *(u16*)(ptW + q * 256 + ((tl * 2) ^ ((q & 7) << 4))) = f2b(p[s][m][c4][jj]);
        }
  __syncthreads();                 // VT seg0 + Pt visible

  f32x4 Oacc[2][4] = {};
#pragma unroll
  for (int s = 0; s < 2; ++s){
#pragma unroll
    for (int kk = 0; kk < 2; ++kk){
      short8 pa[2];
#pragma unroll
      for (int m = 0; m < 2; ++m)
        pa[m] = *(const short8*)(ptW + (m * 16 + l15) * 256 + ((s * 128 + kk * 64 + (grp << 4)) ^ ((l15 & 7) << 4)));
#pragma unroll
      for (int dt = 0; dt < 4; ++dt){
        int dr = dt * 16 + l15;
        short8 vb = *(const short8*)(kvS + dr * 1024 + ((wave * 128 + kk * 64 + (grp << 4)) ^ ((dr & 31) << 4)));
#pragma unroll
        for (int m = 0; m < 2; ++m)
          Oacc[m][dt] = __builtin_amdgcn_mfma_f32_16x16x32_bf16(pa[m], vb, Oacc[m][dt], 0, 0, 0);
      }
    }
    if (s == 0){
      __syncthreads();
#pragma unroll
      for (int i = 0; i < 8; ++i){ int c = tid + i * 512, d = c >> 6, tc = c & 63;
        *(us8*)(kvS + d * 1024 + ((tc * 16) ^ ((d & 31) << 4))) = stv[i]; }
      __syncthreads();
    }
  }

  // cross-wave reduce of partial O
  __syncthreads();
  float* par = (float*)kvS;
#pragma unroll
  for (int m = 0; m < 2; ++m)
#pragma unroll
    for (int dt = 0; dt < 4; ++dt)
#pragma unroll
      for (int jj = 0; jj < 4; ++jj)
        par[wave * 2048 + (m * 16 + (grp << 2) + jj) * 64 + dt * 16 + l15] = Oacc[m][dt][jj];
  __syncthreads();
  {
    f32x4 v = {0.f, 0.f, 0.f, 0.f};
#pragma unroll
    for (int w = 0; w < 8; ++w) v += *(const f32x4*)(par + w * 2048 + tid * 4);
    int q = tid >> 4, d4 = (tid & 15) * 4;
    float il = redf[512 + q];
    us4 pk;
#pragma unroll
    for (int e = 0; e < 4; ++e) pk[e] = f2b(v[e] * il);
    *(us4*)(ctx + ((size_t)(q0 + q) * 8 + bat) * 1024 + head * 64 + d4) = pk;
  }
}

// ---------------- launch ----------------
extern "C" void kernel_launch(void* const* d_in, const int* in_sizes, int n_in,
                              void* d_out, int out_size, void* d_ws, size_t ws_size,
                              hipStream_t stream){
  const float* x   = (const float*)d_in[0];
  const float* pos = (const float*)d_in[1];
  const float* Wi  = (const float*)d_in[2];
  const float* bi  = (const float*)d_in[3];
  const float* Wp  = (const float*)d_in[4];
  const float* bp  = (const float*)d_in[5];
  const float* Wo  = (const float*)d_in[6];
  const float* bo  = (const float*)d_in[7];
  const float* r_i = (const float*)d_in[8];
  const float* s_i = (const float*)d_in[9];
  const float* r_p = (const float*)d_in[10];
  const float* s_p = (const float*)d_in[11];
  const float* rwb = (const float*)d_in[12];
  const float* rrb = (const float*)d_in[13];

  const size_t MB = 1024 * 1024;
  u16* qkv = (u16*)((char*)d_ws);              // 48 MiB (bf16)
  u16* rk  = (u16*)((char*)d_ws + 48 * MB);    // 16 MiB (bf16); ws total 64 MiB
  u16* VTg  = (u16*)d_out;
  u16* ctxg = (u16*)((char*)d_out + 16777216);

  k_gemm<true,  true,  false, false, false><<<dim3(24, 64), 256, 0, stream>>>(x,   Wi, r_i, s_i, bi, qkv, N3_);
  k_gemm<true,  true,  true,  false, false><<<dim3(8, 64),  256, 0, stream>>>(pos, Wp, r_p, s_p, bp, rk, 1024);
  k_vt<<<dim3(16, 128), 256, 0, stream>>>(qkv, VTg);
  k_attn<<<dim3(4096), 512, 0, stream>>>(qkv, rk, VTg, rwb, rrb, ctxg);
  hipMemcpyAsync(qkv, ctxg, (size_t)out_size * sizeof(u16), hipMemcpyDeviceToDevice, stream);
  k_gemm<false, false, false, true, true><<<dim3(8, 64), 256, 0, stream>>>(qkv, Wo, nullptr, nullptr, bo, (float*)d_out, 1024);
}

// Round 8
// 427.891 us; speedup vs baseline: 1.0638x; 1.0638x over previous
//
#include <hip/hip_runtime.h>
#include <cstdint>
#include <cstddef>

using u16 = unsigned short;
typedef short short8 __attribute__((ext_vector_type(8)));
typedef unsigned short us8 __attribute__((ext_vector_type(8)));
typedef unsigned short us4 __attribute__((ext_vector_type(4)));
typedef float f32x4 __attribute__((ext_vector_type(4)));
typedef float f4 __attribute__((ext_vector_type(4)));

#define T_ 1024
#define B_ 8
#define H_ 1024
#define HEADS_ 16
#define HD_ 64
#define N3_ 3072

__device__ __forceinline__ float b2f(u16 u){
  union { float f; unsigned int i; } v; v.i = ((unsigned int)u) << 16; return v.f;
}
// fast bf16 convert: round-half-up
__device__ __forceinline__ u16 f2b(float f){
  union { float f; unsigned int i; } v; v.f = f;
  return (u16)((v.i + 0x8000u) >> 16);
}

// ---------------- GEMM (unchanged from passing rounds) ----------------
template<bool HAS_S, bool SCALE_A, bool POS_A, bool A_BF16, bool OUT_F32>
__global__ __launch_bounds__(256) void k_gemm(const void* __restrict__ A_, const float* __restrict__ W,
                                              const float* __restrict__ RA, const float* __restrict__ S,
                                              const float* __restrict__ bias, void* __restrict__ C_, int N){
  const int K = 1024;
  const int n0 = blockIdx.x * 128, m0 = blockIdx.y * 128;
  const int tid = threadIdx.x, lane = tid & 63;
  const int wave = tid >> 6, wr = wave >> 1, wc = wave & 1;
  __shared__ alignas(16) u16 At[128 * 32];
  __shared__ alignas(16) u16 Bt[128 * 32];
  f32x4 acc[4][4] = {};

  for (int kt = 0; kt < 32; ++kt){
    const int k0 = kt * 32;
    f4 wv[4];
    us8 avb[2];
    f4 avf[4];
#pragma unroll
    for (int i = 0; i < 4; ++i){
      int c = tid + i * 256, r = c >> 3, sg = c & 7;
      wv[i] = *(const f4*)(W + (size_t)(n0 + r) * K + k0 + sg * 4);
    }
    if (A_BF16){
      const u16* A = (const u16*)A_;
#pragma unroll
      for (int i = 0; i < 2; ++i){
        int c = tid + i * 256, r = c >> 2, sg = c & 3;
        avb[i] = *(const us8*)(A + (size_t)(m0 + r) * K + k0 + sg * 8);
      }
    } else {
      const float* A = (const float*)A_;
#pragma unroll
      for (int i = 0; i < 4; ++i){
        int c = tid + i * 256, r = c >> 3, sg = c & 7;
        int m = m0 + r;
        const float* ap = POS_A ? (A + (size_t)(m >> 3) * K + k0 + sg * 4)
                                : (A + (size_t)m * K + k0 + sg * 4);
        avf[i] = *(const f4*)ap;
        if (SCALE_A){
          f4 rv = *(const f4*)(RA + (m & 7) * K + k0 + sg * 4);
          avf[i] = avf[i] * rv;
        }
      }
    }
    __syncthreads();
#pragma unroll
    for (int i = 0; i < 4; ++i){
      int c = tid + i * 256, r = c >> 3, sg = c & 7;
      us4 pw;
#pragma unroll
      for (int u = 0; u < 4; ++u) pw[u] = f2b(wv[i][u]);
      *(us4*)(Bt + r * 32 + sg * 4) = pw;
    }
    if (A_BF16){
#pragma unroll
      for (int i = 0; i < 2; ++i){
        int c = tid + i * 256, r = c >> 2, sg = c & 3;
        *(us8*)(At + r * 32 + sg * 8) = avb[i];
      }
    } else {
#pragma unroll
      for (int i = 0; i < 4; ++i){
        int c = tid + i * 256, r = c >> 3, sg = c & 7;
        us4 pa;
#pragma unroll
        for (int u = 0; u < 4; ++u) pa[u] = f2b(avf[i][u]);
        *(us4*)(At + r * 32 + sg * 4) = pa;
      }
    }
    __syncthreads();
    short8 af[4], bf[4];
#pragma unroll
    for (int i = 0; i < 4; ++i){
      int ar = wr * 64 + i * 16 + (lane & 15);
      af[i] = *(const short8*)(At + ar * 32 + ((lane >> 4) << 3));
      int br = wc * 64 + i * 16 + (lane & 15);
      bf[i] = *(const short8*)(Bt + br * 32 + ((lane >> 4) << 3));
    }
#pragma unroll
    for (int i = 0; i < 4; ++i)
#pragma unroll
      for (int j = 0; j < 4; ++j)
        acc[i][j] = __builtin_amdgcn_mfma_f32_16x16x32_bf16(af[i], bf[j], acc[i][j], 0, 0, 0);
  }
#pragma unroll
  for (int i = 0; i < 4; ++i){
    int row0 = wr * 64 + i * 16 + ((lane >> 4) << 2);
#pragma unroll
    for (int j = 0; j < 4; ++j){
      int o = n0 + wc * 64 + j * 16 + (lane & 15);
      float bv = bias[o];
#pragma unroll
      for (int jj = 0; jj < 4; ++jj){
        int m = m0 + row0 + jj;
        float v = acc[i][j][jj];
        if (HAS_S) v *= S[(m & 7) * N + o];
        v += bv;
        if (OUT_F32) ((float*)C_)[(size_t)m * N + o] = v;
        else         ((u16*)C_)[(size_t)m * N + o] = f2b(v);
      }
    }
  }
}

// ---------------- V transpose to global: VT[n][d][t] <- qkv[t, b, head*192+128+d] ----------------
__global__ __launch_bounds__(256) void k_vt(const u16* __restrict__ qkv, u16* __restrict__ VT){
  const int tt = blockIdx.x;
  const int n = blockIdx.y;
  const int b = n >> 4, head = n & 15;
  __shared__ alignas(16) u16 tile[64][72];
  const int tid = threadIdx.x;
#pragma unroll
  for (int i = 0; i < 2; ++i){
    int c = tid + i * 256;
    int r = c >> 3, sg = c & 7;
    const u16* src = qkv + ((size_t)(tt * 64 + r) * 8 + b) * N3_ + head * 192 + 128 + sg * 8;
    *(us8*)&tile[r][sg * 8] = *(const us8*)src;
  }
  __syncthreads();
#pragma unroll
  for (int i = 0; i < 2; ++i){
    int c = tid + i * 256;
    int d = c >> 3, sg = c & 7;
    us8 ov;
#pragma unroll
    for (int u = 0; u < 8; ++u) ov[u] = tile[sg * 8 + u][d];
    *(us8*)(VT + ((size_t)n * 64 + d) * 1024 + tt * 64 + sg * 8) = ov;
  }
}

// ---------------- fused attention ----------------
// 1-D grid 4096, XCD-swizzled. NO LDS staging of K/rk/V: MFMA B-fragments are read
// DIRECTLY from global (16B contiguous, L2-resident per-XCD working set 384KB/n).
// LDS: gS (flat rel-shift g panel) + rwq/rrq + redf = 78KB -> 2 blocks/CU.
#define G_OFF   0           // flat g, 33*1025*2 = 67650 B ; later: per-wave Pt / partials overlay
#define RWQ_OFF 67664       // 32 x 128B
#define RRQ_OFF 71760       // 48 x 128B
#define RED_OFF 77904       // 512 floats
#define SMEM_SZ 79952

__device__ __forceinline__ int gswz(int byt){ return byt ^ (((byt >> 13) & 3) << 5); }

__global__ __launch_bounds__(512, 4) void k_attn(const u16* __restrict__ qkv, const u16* __restrict__ rk,
                                                 const u16* __restrict__ VTg, const float* __restrict__ rwb,
                                                 const float* __restrict__ rrb, u16* __restrict__ ctx){
  const int bid = blockIdx.x;
  const int n = (bid & 7) + ((bid >> 8) << 3);
  const int qb = (bid >> 3) & 31;
  const int q0 = qb * 32;
  const int bat = n >> 4, head = n & 15;
  const int tid = threadIdx.x, lane = tid & 63, wave = tid >> 6;
  const int l15 = lane & 15, grp = lane >> 4;

  __shared__ alignas(16) char smem[SMEM_SZ];
  char* gB  = smem + G_OFF;
  u16* rwq = (u16*)(smem + RWQ_OFF);
  u16* rrq = (u16*)(smem + RRQ_OFF);
  float* redf = (float*)(smem + RED_OFF);

  // ---- Phase A: rw_q + rr_q, bias added, pre-scaled by 0.125*log2(e) (exp2 domain)
  const float PRESCALE = 0.125f * 1.44269504089f;
#pragma unroll
  for (int rep = 0; rep < 2; ++rep){
    int c = tid + rep * 512;
    if (c < 640){
      int s = c >> 3, sg = c & 7;
      u16* dst; int row; const float* bias;
      if (s < 32){ dst = rwq; row = s; bias = rwb; }
      else       { dst = rrq; row = s - 32; bias = rrb; }
      int qrow = q0 + row;
      float v[8];
      const float* bp2 = bias + head * 64 + sg * 8;
      if (qrow < T_){
        const u16* qp = qkv + ((size_t)qrow * 8 + bat) * N3_ + head * 192 + sg * 8;
        us8 qv = *(const us8*)qp;
        f4 b0 = *(const f4*)bp2, b1 = *(const f4*)(bp2 + 4);
#pragma unroll
        for (int u = 0; u < 4; ++u){
          v[u]     = (b2f(qv[u])     + b0[u]) * PRESCALE;
          v[u + 4] = (b2f(qv[u + 4]) + b1[u]) * PRESCALE;
        }
      } else {
#pragma unroll
        for (int u = 0; u < 8; ++u) v[u] = 0.f;
      }
      us8 pk;
#pragma unroll
      for (int u = 0; u < 8; ++u) pk[u] = f2b(v[u]);
      *(us8*)((char*)dst + row * 128 + ((sg * 16) ^ ((row & 7) << 4))) = pk;
    }
  }
  if (tid < 33) *(u16*)(gB + gswz(tid * 2050 + 2048)) = 0;

  auto ldf = [&](const void* base, int row, int kkb)->short8 {
    int co = kkb + (grp << 4);
    return *(const short8*)((const char*)base + row * 128 + (co ^ ((row & 7) << 4)));
  };

  __syncthreads();                 // (1) Phase A + zero slots visible

  // ---- Phase B: g[a][r] = rr_q[q0+a].rk[r], a<33. B-frags direct from global.
#pragma unroll
  for (int s = 0; s < 2; ++s){
    short8 af[3][2];
#pragma unroll
    for (int pi = 0; pi < 3; ++pi)
#pragma unroll
      for (int kk = 0; kk < 2; ++kk) af[pi][kk] = ldf(rrq, pi * 16 + l15, kk * 64);
#pragma unroll
    for (int c4 = 0; c4 < 4; ++c4){
      int r = s * 512 + wave * 64 + c4 * 16 + l15;
      const u16* bp = rk + ((size_t)r * 8 + bat) * 1024 + head * 64 + grp * 8;
      short8 bf0 = *(const short8*)bp;
      short8 bf1 = *(const short8*)(bp + 32);
      int rg = s * 512 + wave * 64 + c4 * 16 + l15;
#pragma unroll
      for (int pi = 0; pi < 3; ++pi){
        f32x4 acc = {0.f, 0.f, 0.f, 0.f};
        acc = __builtin_amdgcn_mfma_f32_16x16x32_bf16(af[pi][0], bf0, acc, 0, 0, 0);
        acc = __builtin_amdgcn_mfma_f32_16x16x32_bf16(af[pi][1], bf1, acc, 0, 0, 0);
#pragma unroll
        for (int jj = 0; jj < 4; ++jj){
          int a = pi * 16 + (grp << 2) + jj;
          if (a < 33) *(u16*)(gB + gswz(a * 2050 + (rg << 1))) = f2b(acc[jj]);
        }
      }
    }
  }
  __syncthreads();                 // (2) gS complete

  // ---- Phase C: scores = AC + rel-shifted BD (branchless flat gather). K direct from global.
  f32x4 p[2][2][4];
  float pm[2][4];
#pragma unroll
  for (int m = 0; m < 2; ++m)
#pragma unroll
    for (int jj = 0; jj < 4; ++jj) pm[m][jj] = -3.0e38f;

#pragma unroll
  for (int s = 0; s < 2; ++s){
    short8 af[2][2];
#pragma unroll
    for (int m = 0; m < 2; ++m)
#pragma unroll
      for (int kk = 0; kk < 2; ++kk) af[m][kk] = ldf(rwq, m * 16 + l15, kk * 64);
#pragma unroll
    for (int c4 = 0; c4 < 4; ++c4){
      int bcol = s * 512 + wave * 64 + c4 * 16 + l15;
      const u16* kp = qkv + ((size_t)bcol * 8 + bat) * N3_ + head * 192 + 64 + grp * 8;
      short8 bf0 = *(const short8*)kp;
      short8 bf1 = *(const short8*)(kp + 32);
      int byt0 = ((1023 - q0 + bcol) << 1) + (grp << 13);
#pragma unroll
      for (int m = 0; m < 2; ++m){
        f32x4 acc = {0.f, 0.f, 0.f, 0.f};
        acc = __builtin_amdgcn_mfma_f32_16x16x32_bf16(af[m][0], bf0, acc, 0, 0, 0);
        acc = __builtin_amdgcn_mfma_f32_16x16x32_bf16(af[m][1], bf1, acc, 0, 0, 0);
#pragma unroll
        for (int jj = 0; jj < 4; ++jj){
          int byt = byt0 + (m << 15) + (jj << 11);
          float gv = b2f(*(const u16*)(gB + gswz(byt)));
          float sc = acc[jj] + gv;
          p[s][m][c4][jj] = sc;
          pm[m][jj] = fmaxf(pm[m][jj], sc);
        }
      }
    }
  }

  // ---- softmax: max reduce
#pragma unroll
  for (int m = 0; m < 2; ++m)
#pragma unroll
    for (int jj = 0; jj < 4; ++jj)
#pragma unroll
      for (int mk = 1; mk < 16; mk <<= 1) pm[m][jj] = fmaxf(pm[m][jj], __shfl_xor(pm[m][jj], mk));
  if (l15 == 0){
#pragma unroll
    for (int m = 0; m < 2; ++m)
#pragma unroll
      for (int jj = 0; jj < 4; ++jj) redf[wave * 32 + m * 16 + (grp << 2) + jj] = pm[m][jj];
  }
  __syncthreads();                 // (3) pm visible; all gS reads done (Pt overlay safe)
  float M_[2][4];
#pragma unroll
  for (int m = 0; m < 2; ++m)
#pragma unroll
    for (int jj = 0; jj < 4; ++jj){
      int row = m * 16 + (grp << 2) + jj;
      float v = redf[row];
#pragma unroll
      for (int w = 1; w < 8; ++w) v = fmaxf(v, redf[w * 32 + row]);
      M_[m][jj] = v;
    }

  // ---- exp2, L accumulate, write P tile (per-wave private region overlaying gS)
  char* ptW = smem + G_OFF + wave * 8192;   // [32 q][128 tl] u16, 256B rows, swizzled
  float L_[2][4] = {};
#pragma unroll
  for (int s = 0; s < 2; ++s)
#pragma unroll
    for (int m = 0; m < 2; ++m)
#pragma unroll
      for (int c4 = 0; c4 < 4; ++c4)
#pragma unroll
        for (int jj = 0; jj < 4; ++jj){
          float e = __builtin_exp2f(p[s][m][c4][jj] - M_[m][jj]);
          L_[m][jj] += e;
          int q = m * 16 + (grp << 2) + jj;
          int tl = s * 64 + c4 * 16 + l15;
          *(u16*)(ptW + q * 256 + ((tl * 2) ^ ((q & 7) << 4))) = f2b(e);
        }
#pragma unroll
  for (int m = 0; m < 2; ++m)
#pragma unroll
    for (int jj = 0; jj < 4; ++jj)
#pragma unroll
      for (int mk = 1; mk < 16; mk <<= 1) L_[m][jj] += __shfl_xor(L_[m][jj], mk);
  if (l15 == 0){
#pragma unroll
    for (int m = 0; m < 2; ++m)
#pragma unroll
      for (int jj = 0; jj < 4; ++jj) redf[256 + wave * 32 + m * 16 + (grp << 2) + jj] = L_[m][jj];
  }
  __syncthreads();                 // (4) L + Pt visible (Pt only self-read, but L needed)

  // ---- Phase D: O = P x V. V fragments direct from global VT. Wave owns 64 t per seg.
  f32x4 Oacc[2][4] = {};
#pragma unroll
  for (int s = 0; s < 2; ++s){
#pragma unroll
    for (int kk = 0; kk < 2; ++kk){
      short8 pa[2];
#pragma unroll
      for (int m = 0; m < 2; ++m)
        pa[m] = *(const short8*)(ptW + (m * 16 + l15) * 256 + ((s * 128 + kk * 64 + (grp << 4)) ^ ((l15 & 7) << 4)));
      int tg = s * 512 + wave * 64 + kk * 32 + grp * 8;
#pragma unroll
      for (int dt = 0; dt < 4; ++dt){
        int dr = dt * 16 + l15;
        short8 vb = *(const short8*)(VTg + ((size_t)n * 64 + dr) * 1024 + tg);
#pragma unroll
        for (int m = 0; m < 2; ++m)
          Oacc[m][dt] = __builtin_amdgcn_mfma_f32_16x16x32_bf16(pa[m], vb, Oacc[m][dt], 0, 0, 0);
      }
    }
  }

  // ---- partials into own 8KB region (overlays own Pt; same-wave ordering), reduce
  float* par = (float*)ptW;
#pragma unroll
  for (int m = 0; m < 2; ++m)
#pragma unroll
    for (int dt = 0; dt < 4; ++dt)
#pragma unroll
      for (int jj = 0; jj < 4; ++jj)
        par[(m * 16 + (grp << 2) + jj) * 64 + dt * 16 + l15] = Oacc[m][dt][jj];
  __syncthreads();                 // (5) all partials visible
  {
    float* parAll = (float*)(smem + G_OFF);
    f32x4 v = {0.f, 0.f, 0.f, 0.f};
#pragma unroll
    for (int w = 0; w < 8; ++w) v += *(const f32x4*)(parAll + w * 2048 + tid * 4);
    int q = tid >> 4, d4 = (tid & 15) * 4;
    float sum = 0.f;
#pragma unroll
    for (int w = 0; w < 8; ++w) sum += redf[256 + w * 32 + q];
    float il = 1.0f / (sum + 1e-20f);
    us4 pk;
#pragma unroll
    for (int e = 0; e < 4; ++e) pk[e] = f2b(v[e] * il);
    *(us4*)(ctx + ((size_t)(q0 + q) * 8 + bat) * 1024 + head * 64 + d4) = pk;
  }
}

// ---------------- launch ----------------
extern "C" void kernel_launch(void* const* d_in, const int* in_sizes, int n_in,
                              void* d_out, int out_size, void* d_ws, size_t ws_size,
                              hipStream_t stream){
  const float* x   = (const float*)d_in[0];
  const float* pos = (const float*)d_in[1];
  const float* Wi  = (const float*)d_in[2];
  const float* bi  = (const float*)d_in[3];
  const float* Wp  = (const float*)d_in[4];
  const float* bp  = (const float*)d_in[5];
  const float* Wo  = (const float*)d_in[6];
  const float* bo  = (const float*)d_in[7];
  const float* r_i = (const float*)d_in[8];
  const float* s_i = (const float*)d_in[9];
  const float* r_p = (const float*)d_in[10];
  const float* s_p = (const float*)d_in[11];
  const float* rwb = (const float*)d_in[12];
  const float* rrb = (const float*)d_in[13];

  const size_t MB = 1024 * 1024;
  u16* qkv = (u16*)((char*)d_ws);              // 48 MiB (bf16)
  u16* rk  = (u16*)((char*)d_ws + 48 * MB);    // 16 MiB (bf16); ws total 64 MiB
  u16* VTg  = (u16*)d_out;
  u16* ctxg = (u16*)((char*)d_out + 16777216);

  k_gemm<true,  true,  false, false, false><<<dim3(24, 64), 256, 0, stream>>>(x,   Wi, r_i, s_i, bi, qkv, N3_);
  k_gemm<true,  true,  true,  false, false><<<dim3(8, 64),  256, 0, stream>>>(pos, Wp, r_p, s_p, bp, rk, 1024);
  k_vt<<<dim3(16, 128), 256, 0, stream>>>(qkv, VTg);
  k_attn<<<dim3(4096), 512, 0, stream>>>(qkv, rk, VTg, rwb, rrb, ctxg);
  hipMemcpyAsync(qkv, ctxg, (size_t)out_size * sizeof(u16), hipMemcpyDeviceToDevice, stream);
  k_gemm<false, false, false, true, true><<<dim3(8, 64), 256, 0, stream>>>(qkv, Wo, nullptr, nullptr, bo, (float*)d_out, 1024);
}